// Round 9
// baseline (181.977 us; speedup 1.0000x reference)
//
#include <hip/hip_runtime.h>

// Shapes (fixed by the problem):
#define F   256   // NUM_FEATURES
#define T   64    // SEQ (token axis)
#define NH  8     // heads
#define D   32    // head dim
#define NA  8     // agents
#define NBB 32    // batch per agent

typedef unsigned short ushortT;
typedef unsigned int   uintT;

typedef short bf16x8 __attribute__((ext_vector_type(8)));
typedef float f32x4  __attribute__((ext_vector_type(4)));

__device__ __forceinline__ float bf2f(ushortT u) {
    union { uintT i; float f; } c; c.i = ((uintT)u) << 16; return c.f;
}
__device__ __forceinline__ ushortT f2bf(float f) {
    union { float f; uintT u; } c; c.f = f;
    uintT u = c.u;
    uintT r = u + 0x7fffu + ((u >> 16) & 1u);   // RNE (cold paths)
    return (ushortT)(r >> 16);
}
__device__ __forceinline__ uintT asu(float f) {
    union { float f; uintT u; } c; c.f = f; return c.u;
}
// Fast pack: bf16(a) | bf16(b)<<16, round-half-up via +0x8000 then v_perm.
// 3 VALU ops per pair (vs ~9 for software RNE). Tie-rounding differs from
// RNE only on exact .5 ulp ties — numerically negligible.
__device__ __forceinline__ uintT pk2bf(float a, float b) {
    uintT ua = asu(a) + 0x8000u;
    uintT ub = asu(b) + 0x8000u;
    return __builtin_amdgcn_perm(ub, ua, 0x07060302u);   // [ub3 ub2 ua3 ua2]
}

// Runtime dtype detection (R3-R8 verified: harness inputs are fp32).
__device__ __forceinline__ int detect_isbf16(const void* xraw) {
    const uintT* w = (const uintT*)xraw;
    int bad = 0;
    for (int k = 0; k < 128; ++k) {
        uintT v = w[k];
        uintT e0 = (v >> 7)  & 0xffu;
        uintT e1 = (v >> 23) & 0xffu;
        bad += (e0 > 131u) + (e1 > 131u);
    }
    return bad == 0 ? 1 : 0;
}

__device__ __forceinline__ ushortT cvt_elem(const void* p, size_t i, bool isbf) {
    return isbf ? ((const ushortT*)p)[i] : f2bf(((const float*)p)[i]);
}

__device__ __forceinline__ void packc(const f32x4 v, float scale, uintT& u0, uintT& u1) {
    u0 = pk2bf(v[0] * scale, v[1] * scale);
    u1 = pk2bf(v[2] * scale, v[3] * scale);
}

// C-layout -> A/B-fragment transform via register shuffles (R6-R8 verified).
__device__ __forceinline__ bf16x8 build_frag(uintT u0a, uintT u1a, uintT u0b, uintT u1b,
                                             int sl0, int sl1, bool hi) {
    union { uintT u[4]; bf16x8 v; } r;
    uintT x0a = (uintT)__shfl((int)u0a, sl0), x0b = (uintT)__shfl((int)u0b, sl0);
    uintT x1a = (uintT)__shfl((int)u1a, sl0), x1b = (uintT)__shfl((int)u1b, sl0);
    uintT x2a = (uintT)__shfl((int)u0a, sl1), x2b = (uintT)__shfl((int)u0b, sl1);
    uintT x3a = (uintT)__shfl((int)u1a, sl1), x3b = (uintT)__shfl((int)u1b, sl1);
    r.u[0] = hi ? x0b : x0a;
    r.u[1] = hi ? x1b : x1a;
    r.u[2] = hi ? x2b : x2a;
    r.u[3] = hi ? x3b : x3a;
    return r.v;
}

// 32-row LDS tile, chunk-XOR swizzle (R8-verified conflict-free pattern).
__device__ __forceinline__ int xposU(int t, int f) {
    return t * 256 + ((((f >> 3) ^ (t & 31)) * 8) | (f & 7));
}
#define FRAGPOS(t_, ks_, quad_) \
    ((t_) * 256 + ((((4 * (ks_) + (quad_)) ^ ((t_) & 31)) * 8)))
// 16-row variant for the attn kernel
__device__ __forceinline__ int xposU16(int t, int f) {
    return t * 256 + ((((f >> 3) ^ t) & 31) * 8) + (f & 7);
}
#define FRAGPOS16(t_, ks_, quad_) \
    ((t_) * 256 + ((((4 * (ks_) + (quad_)) ^ (t_)) & 31) * 8))

// ===========================================================================
// ws layout (bytes) — needA = 17301504:
//   0        Wt   [c'=1024][f=256] bf16   524288
//            (c'<256:Q, <512:K, <768:V, >=768: Wp[g][c])
//   524288   Kws  [nb][h][s][d] bf16     8388608
//   8912896  Vws  [nb][h][d][s] bf16     8388608  (transposed)
// ===========================================================================

// K0: weight prep. 262144 elems, grid 128 x 256, 8 elems/thread.
__global__ __launch_bounds__(256) void wprep_kernel(const void* __restrict__ Wq,
                                                    const void* __restrict__ Wk,
                                                    const void* __restrict__ Wv,
                                                    const void* __restrict__ Wp,
                                                    const void* __restrict__ x,
                                                    ushortT* __restrict__ Wt) {
    __shared__ int sflag;
    if (threadIdx.x == 0) sflag = detect_isbf16(x);
    __syncthreads();
    bool isbf = sflag != 0;

    int base = (blockIdx.x * 256 + threadIdx.x) * 8;   // < 262144
    int cp = base >> 8, f0 = base & 255;

    ushortT tmp[8];
    if (cp < 768) {   // QKV: transpose W*[h][f][d] -> Wt[c'][f]
        int qkv = cp >> 8, c = cp & 255, hh = c >> 5, d = c & 31;
        const void* W = (qkv == 0) ? Wq : (qkv == 1) ? Wk : Wv;
        #pragma unroll
        for (int jj = 0; jj < 8; ++jj)
            tmp[jj] = cvt_elem(W, (size_t)(hh * F + f0 + jj) * D + d, isbf);
    } else {          // Wp[g][c] straight copy
        int g = cp - 768;
        #pragma unroll
        for (int jj = 0; jj < 8; ++jj)
            tmp[jj] = cvt_elem(Wp, (size_t)g * F + f0 + jj, isbf);
    }
    *(uint4*)&Wt[base] = *(const uint4*)tmp;
}

// Stage full x[nb] tile -> xs (two stacked 32-row swizzled tiles), qkv use.
__device__ __forceinline__ void stage_xT(const void* x, int nb, ushortT* xs,
                                         bool isbf, int tid) {
    int t = tid & 63;
    int g0 = tid >> 6;   // 4 groups per wave-set, 64 total over 16 iters
    #pragma unroll
    for (int it = 0; it < 16; ++it) {
        int g = g0 + it * 4;
        float v0, v1, v2, v3;
        if (isbf) {
            const ushortT* xp = (const ushortT*)x + (size_t)nb * (F * T) + (size_t)g * 4 * T + t;
            v0 = bf2f(xp[0]); v1 = bf2f(xp[T]); v2 = bf2f(xp[2 * T]); v3 = bf2f(xp[3 * T]);
        } else {
            const float* xp = (const float*)x + (size_t)nb * (F * T) + (size_t)g * 4 * T + t;
            v0 = xp[0]; v1 = xp[T]; v2 = xp[2 * T]; v3 = xp[3 * T];
        }
        *(uint2*)&xs[xposU(t & 31, g * 4) + (t >> 5) * 8192] =
            make_uint2(pk2bf(v0, v1), pk2bf(v2, v3));
    }
}

// ---------------------------------------------------------------------------
// K1: K/V projection GEMM.  grid (nb=256, part=4), 256 thr (4 waves).
// part p: is_v = p>>1, sub = p&1 -> 128 rows per block, 32 per wave (2 m-tiles).
// 1024 blocks = 4/CU for latency overlap.
// ---------------------------------------------------------------------------
__global__ __launch_bounds__(256, 4) void qkv_kernel(const void* __restrict__ x,
                                                     const ushortT* __restrict__ Wt,
                                                     ushortT* __restrict__ Kws,
                                                     ushortT* __restrict__ Vws) {
    int nb = blockIdx.x, part = blockIdx.y;
    int is_v = part >> 1, sub = part & 1;
    __shared__ __align__(16) ushortT xs[T * F];   // 32 KB
    __shared__ int sflag;
    int tid = threadIdx.x;
    if (tid == 0) sflag = detect_isbf16(x);
    __syncthreads();
    bool isbf = sflag != 0;
    stage_xT(x, nb, xs, isbf, tid);
    __syncthreads();

    int w = tid >> 6, lane = tid & 63, l15 = lane & 15, quad = lane >> 4;
    int rowbase = 256 + 256 * is_v + 128 * sub + 32 * w;

    f32x4 acc[2][4];
    #pragma unroll
    for (int a = 0; a < 2; ++a)
        #pragma unroll
        for (int c = 0; c < 4; ++c) acc[a][c] = (f32x4){0.f, 0.f, 0.f, 0.f};

    #pragma unroll
    for (int ks = 0; ks < 8; ++ks) {
        bf16x8 Bfr[4];
        #pragma unroll
        for (int nt = 0; nt < 4; ++nt) {
            int t = 16 * nt + l15;
            Bfr[nt] = *(const bf16x8*)&xs[FRAGPOS(t & 31, ks, quad) + (t >> 5) * 8192];
        }
        #pragma unroll
        for (int mt = 0; mt < 2; ++mt) {
            bf16x8 Afr = *(const bf16x8*)(Wt +
                (size_t)(rowbase + 16 * mt + l15) * 256 + ks * 32 + quad * 8);
            #pragma unroll
            for (int nt = 0; nt < 4; ++nt)
                acc[mt][nt] = __builtin_amdgcn_mfma_f32_16x16x32_bf16(Afr, Bfr[nt],
                                                                      acc[mt][nt], 0, 0, 0);
        }
    }

    #pragma unroll
    for (int mt = 0; mt < 2; ++mt) {
        int rel = 128 * sub + 32 * w + 16 * mt + 4 * quad;   // 0..255 in K or V block
        int hh = rel >> 5, db = rel & 31;
        #pragma unroll
        for (int nt = 0; nt < 4; ++nt) {
            int t = 16 * nt + l15;
            f32x4 v = acc[mt][nt];
            if (is_v == 0) {   // K: [nb][h][s=t][d]
                ushortT* dst = Kws + ((size_t)(nb * NH + hh) * T + t) * D + db;
                *(uint2*)dst = make_uint2(pk2bf(v[0], v[1]), pk2bf(v[2], v[3]));
            } else {           // V transposed: [nb][h][d][s=t]
                #pragma unroll
                for (int r = 0; r < 4; ++r)
                    Vws[((size_t)(nb * NH + hh) * D + db + r) * T + t] = f2bf(v[r]);
            }
        }
    }
}

// ---------------------------------------------------------------------------
// K2: Q-GEMM + attention + projection over a 16-token quarter.
// grid (b=32, j=8, tb=4) = 1024 blocks (4/CU), 512 thr, wave = head h.
// VGPR budget <=64 -> 8 waves/SIMD co-resident. P via register shuffles.
// LDS: xs 8 KB (x quarter-tile, reused as Y) + bpf 1 KB.
// ---------------------------------------------------------------------------
__global__ __launch_bounds__(512, 4) void attn_kernel(const void* __restrict__ x,
                                                      const ushortT* __restrict__ Wt,
                                                      const ushortT* __restrict__ Kws,
                                                      const ushortT* __restrict__ Vws,
                                                      const void* __restrict__ bp,
                                                      void* __restrict__ outp) {
    __shared__ __align__(16) ushortT xs[16 * F];   // 8 KB
    __shared__ float bpf[F];
    __shared__ int sflag;

    int tid = threadIdx.x;
    int b = blockIdx.x, j = blockIdx.y, tb = blockIdx.z;
    int nbj = j * NBB + b;

    if (tid == 0) sflag = detect_isbf16(x);
    __syncthreads();
    bool isbf = sflag != 0;

    // stage x quarter-tile: lane = local t (0..15), 32 f-groups x 2 iters
    {
        int t = tid & 15, fg = tid >> 4;   // fg 0..31
        int ta = tb * 16 + t;
        #pragma unroll
        for (int it = 0; it < 2; ++it) {
            int f0 = (fg + 32 * it) * 4;
            float v0, v1, v2, v3;
            if (isbf) {
                const ushortT* xp = (const ushortT*)x + (size_t)nbj * (F * T) +
                                    (size_t)f0 * T + ta;
                v0 = bf2f(xp[0]); v1 = bf2f(xp[T]); v2 = bf2f(xp[2 * T]); v3 = bf2f(xp[3 * T]);
            } else {
                const float* xp = (const float*)x + (size_t)nbj * (F * T) +
                                  (size_t)f0 * T + ta;
                v0 = xp[0]; v1 = xp[T]; v2 = xp[2 * T]; v3 = xp[3 * T];
            }
            *(uint2*)&xs[xposU16(t, f0)] = make_uint2(pk2bf(v0, v1), pk2bf(v2, v3));
        }
    }
    if (tid < 256)
        bpf[tid] = isbf ? bf2f(((const ushortT*)bp)[tid]) : ((const float*)bp)[tid];
    __syncthreads();

    int h = tid >> 6, lane = tid & 63, l15 = lane & 15, quad = lane >> 4;
    bool hi = quad >= 2;
    int sl0 = l15 + 32 * (quad & 1), sl1 = sl0 + 16;

    // ---- Q-GEMM: rows 32h..32h+31, cols = 16 local t; softmax scale folded
    bf16x8 qf;
    {
        f32x4 qacc[2];
        qacc[0] = (f32x4){0.f, 0.f, 0.f, 0.f};
        qacc[1] = (f32x4){0.f, 0.f, 0.f, 0.f};
        #pragma unroll
        for (int ks = 0; ks < 8; ++ks) {
            bf16x8 xf = *(const bf16x8*)&xs[FRAGPOS16(l15, ks, quad)];
            #pragma unroll
            for (int mt = 0; mt < 2; ++mt) {
                bf16x8 Aw = *(const bf16x8*)(Wt +
                    (size_t)(32 * h + 16 * mt + l15) * 256 + ks * 32 + quad * 8);
                qacc[mt] = __builtin_amdgcn_mfma_f32_16x16x32_bf16(
                    Aw, xf, qacc[mt], 0, 0, 0);
            }
        }
        uintT a0, a1, b0, b1;
        packc(qacc[0], 0.0625f, a0, a1);
        packc(qacc[1], 0.0625f, b0, b1);
        qf = build_frag(a0, a1, b0, b1, sl0, sl1, hi);
    }

    f32x4 oacc[2];
    oacc[0] = (f32x4){0.f, 0.f, 0.f, 0.f};
    oacc[1] = (f32x4){0.f, 0.f, 0.f, 0.f};

    // ---- key-agent loop (no barriers)
    for (int i = 0; i < NA; ++i) {
        int nbi = i * NBB + b;
        const ushortT* Kb = Kws + (size_t)(nbi * NH + h) * T * D;
        const ushortT* Vb = Vws + (size_t)(nbi * NH + h) * D * T;

        float psum = 0.f;
        f32x4 pv[2];
        pv[0] = (f32x4){0.f, 0.f, 0.f, 0.f};
        pv[1] = (f32x4){0.f, 0.f, 0.f, 0.f};

        #pragma unroll
        for (int kx = 0; kx < 2; ++kx) {
            uintT pu0[2], pu1[2];
            #pragma unroll
            for (int sp = 0; sp < 2; ++sp) {
                bf16x8 kf = *(const bf16x8*)(Kb + (16 * (2 * kx + sp) + l15) * D + quad * 8);
                f32x4 s4 = __builtin_amdgcn_mfma_f32_16x16x32_bf16(
                    kf, qf, (f32x4){0.f, 0.f, 0.f, 0.f}, 0, 0, 0);
                #pragma unroll
                for (int r = 0; r < 4; ++r) {
                    float e = __expf(s4[r]);
                    s4[r] = e;
                    psum += e;
                }
                packc(s4, 1.f, pu0[sp], pu1[sp]);
            }
            bf16x8 pf = build_frag(pu0[0], pu1[0], pu0[1], pu1[1], sl0, sl1, hi);
            bf16x8 vf0 = *(const bf16x8*)(Vb + l15 * T + kx * 32 + quad * 8);
            bf16x8 vf1 = *(const bf16x8*)(Vb + (16 + l15) * T + kx * 32 + quad * 8);
            pv[0] = __builtin_amdgcn_mfma_f32_16x16x32_bf16(vf0, pf, pv[0], 0, 0, 0);
            pv[1] = __builtin_amdgcn_mfma_f32_16x16x32_bf16(vf1, pf, pv[1], 0, 0, 0);
        }

        psum += __shfl_xor(psum, 16);
        psum += __shfl_xor(psum, 32);
        float inv = 1.0f / psum;
        #pragma unroll
        for (int mt = 0; mt < 2; ++mt)
            #pragma unroll
            for (int r = 0; r < 4; ++r)
                oacc[mt][r] = fmaf(inv, pv[mt][r], oacc[mt][r]);
    }

    // ---- epilogue: Y[t16][c] -> xs (swizzled), then projection
    __syncthreads();
    #pragma unroll
    for (int mt = 0; mt < 2; ++mt) {
        int cb = 32 * h + 16 * mt + 4 * quad;
        uintT u0, u1;
        packc(oacc[mt], 1.f, u0, u1);
        *(uint2*)&xs[xposU16(l15, cb)] = make_uint2(u0, u1);
    }
    __syncthreads();

    // OUT[g][t16] = Wp[g][c] . Y[t][c] + bp[g];  wave h -> g-tiles 2h, 2h+1
    f32x4 cacc[2];
    cacc[0] = (f32x4){0.f, 0.f, 0.f, 0.f};
    cacc[1] = (f32x4){0.f, 0.f, 0.f, 0.f};

    #pragma unroll
    for (int ks = 0; ks < 8; ++ks) {
        bf16x8 yb = *(const bf16x8*)&xs[FRAGPOS16(l15, ks, quad)];
        #pragma unroll
        for (int m2 = 0; m2 < 2; ++m2) {
            int g = 16 * (2 * h + m2) + l15;
            bf16x8 wf = *(const bf16x8*)(Wt + (size_t)(768 + g) * 256 + ks * 32 + quad * 8);
            cacc[m2] = __builtin_amdgcn_mfma_f32_16x16x32_bf16(wf, yb, cacc[m2], 0, 0, 0);
        }
    }

    #pragma unroll
    for (int m2 = 0; m2 < 2; ++m2) {
        int t = tb * 16 + l15;
        #pragma unroll
        for (int r = 0; r < 4; ++r) {
            int g = 16 * (2 * h + m2) + 4 * quad + r;
            float val = cacc[m2][r] + bpf[g];
            if (isbf)
                ((ushortT*)outp)[(size_t)nbj * F * T + g * T + t] = f2bf(val);
            else
                ((float*)outp)[(size_t)nbj * F * T + g * T + t] = val;
        }
    }
}

// ===========================================================================
// PATH B: zero-workspace scalar fallback (R3-verified, dtype-flexible).
// ===========================================================================
__device__ __forceinline__ float tof(ushortT u) { return bf2f(u); }
__device__ __forceinline__ float tof(float f)   { return f; }

__device__ __forceinline__ void stage_x(const void* x, size_t nb, ushortT* sX,
                                        bool isbf, int tid) {
    if (isbf) {
        const int4* xg = (const int4*)((const ushortT*)x + nb * (F * T));
        int4* xl = (int4*)sX;
        for (int kk = tid; kk < F * T / 8; kk += 512) xl[kk] = xg[kk];
    } else {
        const float4* xg = (const float4*)((const float*)x + nb * (F * T));
        for (int kk = tid; kk < F * T / 4; kk += 512) {
            float4 v = xg[kk];
            int o = kk * 4;
            sX[o + 0] = f2bf(v.x); sX[o + 1] = f2bf(v.y);
            sX[o + 2] = f2bf(v.z); sX[o + 3] = f2bf(v.w);
        }
    }
}

template <typename WT>
__device__ __forceinline__ void q_proj(const WT* __restrict__ W, const ushortT* sX,
                                       ushortT* dst, int c, int t0) {
    float acc[32];
    #pragma unroll
    for (int m = 0; m < 32; ++m) acc[m] = 0.f;
    for (int f = 0; f < F; ++f) {
        float w = tof(W[f * D]);
        const ushortT* xr = &sX[f * T + t0];
        #pragma unroll
        for (int m = 0; m < 32; ++m) acc[m] = fmaf(bf2f(xr[m]), w, acc[m]);
    }
    #pragma unroll
    for (int m = 0; m < 32; ++m) dst[(t0 + m) * F + c] = f2bf(acc[m]);
}

template <typename WT>
__device__ __forceinline__ void kv_proj(const WT* __restrict__ WK, const WT* __restrict__ WV,
                                        const ushortT* sX, ushortT* sK, ushortT* sV,
                                        int c, int t0) {
    float ak[32], av[32];
    #pragma unroll
    for (int m = 0; m < 32; ++m) { ak[m] = 0.f; av[m] = 0.f; }
    for (int f = 0; f < F; ++f) {
        float wk = tof(WK[f * D]);
        float wv = tof(WV[f * D]);
        const ushortT* xr = &sX[f * T + t0];
        #pragma unroll
        for (int m = 0; m < 32; ++m) {
            float xv = bf2f(xr[m]);
            ak[m] = fmaf(xv, wk, ak[m]);
            av[m] = fmaf(xv, wv, av[m]);
        }
    }
    #pragma unroll
    for (int m = 0; m < 32; ++m) {
        sK[(t0 + m) * F + c] = f2bf(ak[m]);
        sV[(t0 + m) * F + c] = f2bf(av[m]);
    }
}

__global__ __launch_bounds__(512) void fused_kernel(const void* __restrict__ x,
                                                    const void* __restrict__ Wq,
                                                    const void* __restrict__ Wk,
                                                    const void* __restrict__ Wv,
                                                    const void* __restrict__ Wp,
                                                    const void* __restrict__ bp,
                                                    void* __restrict__ outp) {
    __shared__ __align__(16) char smem[98304];
    __shared__ int sflag;
    ushortT* sX = (ushortT*)smem;
    ushortT* sK = (ushortT*)(smem + 32768);
    ushortT* sV = (ushortT*)(smem + 65536);
    float*   sO = (float*)smem;

    int tid = threadIdx.x;
    int b = blockIdx.x, j = blockIdx.y;
    size_t nbj = (size_t)j * NBB + b;

    if (tid == 0) sflag = detect_isbf16(x);
    __syncthreads();
    bool isbf = sflag != 0;

    stage_x(x, nbj, sX, isbf, tid);
    __syncthreads();

    int c = tid & 255, t0 = (tid >> 8) * 32;
    int hc = c >> 5, dc = c & 31;
    if (isbf) q_proj((const ushortT*)Wq + (size_t)hc * F * D + dc, sX, sK, c, t0);
    else      q_proj((const float*)Wq   + (size_t)hc * F * D + dc, sX, sK, c, t0);
    __syncthreads();

    int h = tid >> 6, t = tid & 63;
    float q[32], o[32];
    #pragma unroll
    for (int dd = 0; dd < 32; ++dd) { q[dd] = bf2f(sK[t * F + h * D + dd]); o[dd] = 0.f; }

    for (int i = 0; i < NA; ++i) {
        __syncthreads();
        stage_x(x, (size_t)(i * NBB + b), sX, isbf, tid);
        __syncthreads();
        if (isbf) kv_proj((const ushortT*)Wk + (size_t)hc * F * D + dc,
                          (const ushortT*)Wv + (size_t)hc * F * D + dc, sX, sK, sV, c, t0);
        else      kv_proj((const float*)Wk   + (size_t)hc * F * D + dc,
                          (const float*)Wv   + (size_t)hc * F * D + dc, sX, sK, sV, c, t0);
        __syncthreads();
        float l = 0.f;
        float oi[32];
        #pragma unroll
        for (int dd = 0; dd < 32; ++dd) oi[dd] = 0.f;
        for (int s = 0; s < T; ++s) {
            const ushortT* kr = &sK[s * F + h * D];
            float dot = 0.f;
            #pragma unroll
            for (int dd = 0; dd < 32; ++dd) dot = fmaf(q[dd], bf2f(kr[dd]), dot);
            float e = __expf(dot * 0.0625f);
            l += e;
            const ushortT* vr = &sV[s * F + h * D];
            #pragma unroll
            for (int dd = 0; dd < 32; ++dd) oi[dd] = fmaf(e, bf2f(vr[dd]), oi[dd]);
        }
        float inv = 1.0f / l;
        #pragma unroll
        for (int dd = 0; dd < 32; ++dd) o[dd] = fmaf(inv, oi[dd], o[dd]);
    }
    __syncthreads();

    #pragma unroll
    for (int dd = 0; dd < 32; ++dd) sO[(h * D + dd) * T + t] = o[dd];
    __syncthreads();

    {
        int g = tid >> 1, te0 = (tid & 1) * 32;
        float acc[32];
        #pragma unroll
        for (int m = 0; m < 32; ++m) acc[m] = 0.f;
        if (isbf) {
            const ushortT* Wrow = (const ushortT*)Wp + (size_t)g * F;
            for (int cc = 0; cc < F; ++cc) {
                float w = bf2f(Wrow[cc]);
                const float* yr = &sO[cc * T + te0];
                #pragma unroll
                for (int m = 0; m < 32; ++m) acc[m] = fmaf(yr[m], w, acc[m]);
            }
        } else {
            const float* Wrow = (const float*)Wp + (size_t)g * F;
            for (int cc = 0; cc < F; ++cc) {
                float w = Wrow[cc];
                const float* yr = &sO[cc * T + te0];
                #pragma unroll
                for (int m = 0; m < 32; ++m) acc[m] = fmaf(yr[m], w, acc[m]);
            }
        }
        float bias = isbf ? bf2f(((const ushortT*)bp)[g]) : ((const float*)bp)[g];
        if (isbf) {
            ushortT* ob = (ushortT*)outp + nbj * F * T + g * T + te0;
            #pragma unroll
            for (int m = 0; m < 32; ++m) ob[m] = f2bf(acc[m] + bias);
        } else {
            float* ob = (float*)outp + nbj * F * T + g * T + te0;
            #pragma unroll
            for (int m = 0; m < 32; ++m) ob[m] = acc[m] + bias;
        }
    }
}

// ---------------------------------------------------------------------------
extern "C" void kernel_launch(void* const* d_in, const int* in_sizes, int n_in,
                              void* d_out, int out_size, void* d_ws, size_t ws_size,
                              hipStream_t stream) {
    const void* x  = d_in[0];
    const void* Wq = d_in[1];
    const void* Wk = d_in[2];
    const void* Wv = d_in[3];
    const void* Wp = d_in[4];
    const void* bp = d_in[5];

    const size_t needA = 17301504;   // Wt(1024 rows) + Kws + Vws

    if (ws_size >= needA) {
        char* ws = (char*)d_ws;
        ushortT* Wt  = (ushortT*)(ws + 0);
        ushortT* Kws = (ushortT*)(ws + 524288);
        ushortT* Vws = (ushortT*)(ws + 8912896);

        wprep_kernel<<<dim3(128),      dim3(256), 0, stream>>>(Wq, Wk, Wv, Wp, x, Wt);
        qkv_kernel  <<<dim3(256, 4),   dim3(256), 0, stream>>>(x, Wt, Kws, Vws);
        attn_kernel <<<dim3(32, 8, 4), dim3(512), 0, stream>>>(x, Wt, Kws, Vws, bp, d_out);
    } else {
        fused_kernel<<<dim3(32, 8), dim3(512), 0, stream>>>(x, Wq, Wk, Wv, Wp, bp, d_out);
    }
}